// Round 2
// 129.899 us; speedup vs baseline: 1.0410x; 1.0410x over previous
//
#include <hip/hip_runtime.h>
#include <math.h>

// Fused single-kernel DSVF biquad IIR (scipy lfilter DF2T), B=512, T=32768.
// One block per row: 512 threads (8 waves), chunk = 64 samples per thread.
// Built verbatim from the harness-verified 3-kernel building blocks:
//   stage: wave w stages segment w (4096 samples) with the old k_partial
//          stride-65 LDS transpose (scalar LDS ops, verified layout).
//   pass1: per-thread zero-init final state d_t over its 64-sample chunk,
//          x kept in c[16] registers across the scan.
//   scan : old k_scan LDS Kogge-Stone in f64 over 512 chunks (1 chunk/thread,
//          9 steps, uniform-W squaring, P = M^64); exclusive prefix s[t-1]
//          is each chunk's true entering state.
//   pass2: rerun chunk from entering state (f32), y -> same LDS slots,
//          barrier, coalesced float4 stores (mirror of staging).
// HBM traffic: read x once (67 MB) + write y once (67 MB). No workspace.

namespace {
constexpr int kT = 32768;
constexpr int kThreads = 512;           // 8 waves, one block per row
constexpr int kChunk = 64;              // samples per thread
constexpr int kStride = kChunk + 1;     // 65-float chunk stride (verified)
constexpr int kWaveLds = 64 * kStride;  // 4160 floats per wave region
constexpr int kSegQuads = 1024;         // float4s per wave segment
}

__device__ inline void coeffs_f32(const float* g, const float* r,
                                  const float* mhp, const float* mbp,
                                  const float* mlp, float& b0, float& b1,
                                  float& b2, float& a1, float& a2) {
  float graw = g[0], rraw = r[0];
  float sig = 1.0f / (1.0f + expf(-graw));
  float gg = tanf(1.5707963267948966f * sig);            // tan(pi*sigmoid/2)
  float rr = (rraw > 20.0f) ? rraw : log1pf(expf(rraw)); // softplus
  float g2 = gg * gg;
  float m_hp = mhp[0], m_bp = mbp[0], m_lp = mlp[0];
  float B0 = g2 * m_lp + gg * m_bp + m_hp;
  float B1 = 2.0f * g2 * m_lp - 2.0f * m_hp;
  float B2 = g2 * m_lp - gg * m_bp + m_hp;
  float A0 = g2 + 2.0f * rr * gg + 1.0f;
  float A1 = 2.0f * g2 - 2.0f;
  float A2 = g2 - 2.0f * rr * gg + 1.0f;
  float inv = 1.0f / A0;
  b0 = B0 * inv; b1 = B1 * inv; b2 = B2 * inv;
  a1 = A1 * inv; a2 = A2 * inv;
}

#define IIR_STEP(xx, yy)                                         \
  do {                                                           \
    yy = fmaf(b0, xx, z1);                                       \
    z1 = fmaf(na1, yy, fmaf(b1, xx, z2));                        \
    z2 = fmaf(na2, yy, b2 * xx);                                 \
  } while (0)

#define MAT_SQ(w00, w01, w10, w11)                               \
  do {                                                           \
    double t00 = w00 * w00 + w01 * w10;                          \
    double t01 = w00 * w01 + w01 * w11;                          \
    double t10 = w10 * w00 + w11 * w10;                          \
    double t11 = w10 * w01 + w11 * w11;                          \
    w00 = t00; w01 = t01; w10 = t10; w11 = t11;                  \
  } while (0)

__global__ __launch_bounds__(kThreads) void k_fused(
    const float* __restrict__ x, const float* g, const float* r,
    const float* mhp, const float* mbp, const float* mlp,
    float* __restrict__ out) {
  __shared__ float xb[8 * kWaveLds];          // 133,120 B
  __shared__ double s1[kThreads], s2[kThreads];  // 8,192 B

  const int t = threadIdx.x;
  const int lane = t & 63;
  const int wave = t >> 6;
  const size_t rowoff = (size_t)blockIdx.x * kT;

  float b0, b1, b2, a1, a2;
  coeffs_f32(g, r, mhp, mbp, mlp, b0, b1, b2, a1, a2);
  float na1 = -a1, na2 = -a2;

  // ---- stage: wave w -> segment w, old k_partial transpose ---------------
  const float4* xv = (const float4*)(x + rowoff) + wave * kSegQuads;
  float* buf = &xb[wave * kWaveLds];
  float4 c[16];
#pragma unroll
  for (int i = 0; i < 16; ++i) c[i] = xv[i * 64 + lane];  // coalesced 1 KB
#pragma unroll
  for (int i = 0; i < 16; ++i) {
    int f = i * 64 + lane;                      // quad index in segment
    int base = (f >> 4) * kStride + ((f & 15) << 2);
    buf[base] = c[i].x; buf[base + 1] = c[i].y;
    buf[base + 2] = c[i].z; buf[base + 3] = c[i].w;
  }
  __syncthreads();
#pragma unroll
  for (int i = 0; i < 16; ++i) {  // lane reads its own chunk (= chunk index t)
    int base = lane * kStride + (i << 2);
    c[i] = make_float4(buf[base], buf[base + 1], buf[base + 2], buf[base + 3]);
  }

  // ---- pass 1: zero-init chunk final state d_t ---------------------------
  float z1 = 0.f, z2 = 0.f;
#pragma unroll
  for (int i = 0; i < 16; ++i) {
    float y;
    IIR_STEP(c[i].x, y); IIR_STEP(c[i].y, y);
    IIR_STEP(c[i].z, y); IIR_STEP(c[i].w, y);
  }

  // ---- scan: f64 LDS Kogge-Stone over 512 chunks, P = M^64 ---------------
  double w00 = -(double)a1, w01 = 1.0, w10 = -(double)a2, w11 = 0.0;
#pragma unroll
  for (int i = 0; i < 6; ++i) MAT_SQ(w00, w01, w10, w11);  // P = M^64

  double A0 = (double)z1, A1 = (double)z2;
  for (int o = 1; o < kThreads; o <<= 1) {  // 9 steps
    s1[t] = A0; s2[t] = A1;
    __syncthreads();
    double q0 = 0.0, q1 = 0.0;
    if (t >= o) { q0 = s1[t - o]; q1 = s2[t - o]; }
    __syncthreads();
    A0 += w00 * q0 + w01 * q1;
    A1 += w10 * q0 + w11 * q1;
    MAT_SQ(w00, w01, w10, w11);
  }
  s1[t] = A0; s2[t] = A1;
  __syncthreads();
  double e0 = 0.0, e1 = 0.0;
  if (t > 0) { e0 = s1[t - 1]; e1 = s2[t - 1]; }  // entering state of chunk t

  // ---- pass 2: rerun chunk from true entering state ----------------------
  z1 = (float)e0; z2 = (float)e1;
#pragma unroll
  for (int i = 0; i < 16; ++i) {
    float4 o4;
    IIR_STEP(c[i].x, o4.x); IIR_STEP(c[i].y, o4.y);
    IIR_STEP(c[i].z, o4.z); IIR_STEP(c[i].w, o4.w);
    c[i] = o4;
  }
  // write y back to own chunk slots (lane-local vs pass-1 reads; safe)
#pragma unroll
  for (int i = 0; i < 16; ++i) {
    int base = lane * kStride + (i << 2);
    buf[base] = c[i].x; buf[base + 1] = c[i].y;
    buf[base + 2] = c[i].z; buf[base + 3] = c[i].w;
  }
  __syncthreads();

  // ---- coalesced store (mirror of staging) -------------------------------
  float4* yv = (float4*)(out + rowoff) + wave * kSegQuads;
#pragma unroll
  for (int i = 0; i < 16; ++i) {
    int f = i * 64 + lane;
    int base = (f >> 4) * kStride + ((f & 15) << 2);
    yv[f] = make_float4(buf[base], buf[base + 1], buf[base + 2], buf[base + 3]);
  }
}

extern "C" void kernel_launch(void* const* d_in, const int* in_sizes, int n_in,
                              void* d_out, int out_size, void* d_ws,
                              size_t ws_size, hipStream_t stream) {
  const float* x   = (const float*)d_in[0];
  const float* g   = (const float*)d_in[1];
  const float* r   = (const float*)d_in[2];
  const float* mhp = (const float*)d_in[3];
  const float* mbp = (const float*)d_in[4];
  const float* mlp = (const float*)d_in[5];
  float* out = (float*)d_out;
  (void)d_ws; (void)ws_size;

  k_fused<<<512, kThreads, 0, stream>>>(x, g, r, mhp, mbp, mlp, out);
}